// Round 2
// baseline (420.128 us; speedup 1.0000x reference)
//
#include <hip/hip_runtime.h>
#include <hip/hip_bf16.h>

// Problem dims: B=4, N=256, F=64, H=256, A=16, T=3.  BN = 1024 rows.
// Float inputs/outputs may be bf16 or fp32 (detected at runtime); adjacency int32.
// Internal compute fp32 in d_ws.

#define BN_ROWS 1024
#define HDIM 256
#define FDIM 64

// ---------------- workspace layout (float offsets) ----------------
#define OFF_NF      0         // 65536
#define OFF_PREW1   65536     // 16384
#define OFF_PREB1   81920     // 256
#define OFF_PREW2   82176     // 65536
#define OFF_PREB2   147712    // 256
#define OFF_WCAT    147968    // 327680  (256 x 1280) = [W1_i | W1_j | Whh]
#define OFF_BCAT    475648    // 1280    [msg_b1 | 0 | gru_bhh]
#define OFF_W2HAT   476928    // 69632   (272 x 256): rows 0..255 msg_W2, row 256 msg_b2, rest 0
#define OFF_WIH     546560    // 196608  (256 x 768)
#define OFF_BIH     743168    // 768
#define OFF_ROW1    743936    // 65536
#define OFF_ROB1    809472    // 256
#define OFF_ROW2    809728    // 4096
#define OFF_ROB2    813824    // 16
#define CONV_TOTAL  813840
#define OFF_X       813840    // 262144
#define OFF_H       1075984   // 262144
#define OFF_HCAT    1338128   // 1310720 (1024 x 1280) = [hi+b1 | hj | gh]
#define OFF_EHAT    2648848   // 278528  (1024 x 272)
#define OFF_AGG     2927376   // 262144
#define OFF_GI      3189520   // 786432
#define OFF_FLAG    3975952   // 1 int: 0 = bf16 inputs, 1 = fp32 inputs
// total ~15.2 MiB

__device__ __forceinline__ float bf2f(unsigned short u) {
    return __uint_as_float(((unsigned int)u) << 16);
}
// NaN-PROPAGATING relu (fmaxf would launder NaN to 0 and hide bugs)
__device__ __forceinline__ float relu(float v) { return v < 0.f ? 0.f : v; }

__device__ __forceinline__ float ld(const void* p, int i, int isf32) {
    return isf32 ? ((const float*)p)[i] : bf2f(((const unsigned short*)p)[i]);
}

// Detect fp32-vs-bf16 by exponent plausibility of EVEN ushort indices of
// node_features. bf16 data: even idx = real bf16, exp in ~[113,129].
// fp32 data: even idx = low mantissa half, exp ~uniform -> ~85% "insane".
__global__ __launch_bounds__(256) void detect_kernel(const unsigned short* __restrict__ nf,
                                                     int* __restrict__ flag) {
    __shared__ int cnt;
    if (threadIdx.x == 0) cnt = 0;
    __syncthreads();
    int bad = 0;
    for (int i = 0; i < 8; ++i) {
        unsigned short u = nf[(threadIdx.x * 8 + i) * 2];
        int ex = (u >> 7) & 0xFF;
        if ((u & 0x7fff) != 0 && (ex < 100 || ex > 140)) bad++;
    }
    atomicAdd(&cnt, bad);
    __syncthreads();
    if (threadIdx.x == 0) *flag = (cnt > 512) ? 1 : 0;
}

// Convert all params to fp32 in ws; build concatenated/augmented weights.
__global__ __launch_bounds__(256) void convert_kernel(
    const void* nf, const void* preW1, const void* preb1, const void* preW2, const void* preb2,
    const void* msgW1, const void* msgb1, const void* msgW2, const void* msgb2,
    const void* gruWih, const void* gruWhh, const void* grubih, const void* grubhh,
    const void* roW1, const void* rob1, const void* roW2, const void* rob2,
    float* __restrict__ w, const int* __restrict__ flagp)
{
    int e = blockIdx.x * 256 + threadIdx.x;
    if (e >= CONV_TOTAL) return;
    const int f32 = *flagp;
    float v;
    if (e < OFF_PREW1)      v = ld(nf, e - OFF_NF, f32);
    else if (e < OFF_PREB1) v = ld(preW1, e - OFF_PREW1, f32);
    else if (e < OFF_PREW2) v = ld(preb1, e - OFF_PREB1, f32);
    else if (e < OFF_PREB2) v = ld(preW2, e - OFF_PREW2, f32);
    else if (e < OFF_WCAT)  v = ld(preb2, e - OFF_PREB2, f32);
    else if (e < OFF_BCAT) {
        int i = e - OFF_WCAT; int r = i / 1280; int c = i - r * 1280;
        if (c < 256)      v = ld(msgW1, r * 256 + c, f32);                 // W1_i = msg_W1[:H]
        else if (c < 512) v = ld(msgW1, (r + 256) * 256 + (c - 256), f32); // W1_j = msg_W1[H:]
        else              v = ld(gruWhh, r * 768 + (c - 512), f32);
    }
    else if (e < OFF_W2HAT) {
        int i = e - OFF_BCAT;
        if (i < 256)      v = ld(msgb1, i, f32);
        else if (i < 512) v = 0.f;
        else              v = ld(grubhh, i - 512, f32);
    }
    else if (e < OFF_WIH) {
        int i = e - OFF_W2HAT; int r = i >> 8; int c = i & 255;
        if (r < 256)       v = ld(msgW2, r * 256 + c, f32);
        else if (r == 256) v = ld(msgb2, c, f32);   // deg*b2 folded via K-augmentation
        else               v = 0.f;
    }
    else if (e < OFF_BIH)   v = ld(gruWih, e - OFF_WIH, f32);
    else if (e < OFF_ROW1)  v = ld(grubih, e - OFF_BIH, f32);
    else if (e < OFF_ROB1)  v = ld(roW1, e - OFF_ROW1, f32);
    else if (e < OFF_ROW2)  v = ld(rob1, e - OFF_ROB1, f32);
    else if (e < OFF_ROB2)  v = ld(roW2, e - OFF_ROW2, f32);
    else                    v = ld(rob2, e - OFF_ROB2, f32);
    w[e] = v;
}

// Generic fp32 GEMM: C[M,N] = A[M,K] @ B[K,N] (+bias) (+relu).
// 64x64 tile / 256 threads, 4x4 micro-tile, BK=16. M,N %64==0; K %16==0.
__global__ __launch_bounds__(256) void gemm_k(
    const float* __restrict__ A, int lda,
    const float* __restrict__ B, int ldb,
    const float* __restrict__ bias,
    float* __restrict__ C, int ldc,
    int K, int dorelu)
{
    __shared__ float As[16][64];
    __shared__ float Bs[16][68];
    const int t  = threadIdx.x;
    const int bm = blockIdx.y * 64;
    const int bn = blockIdx.x * 64;
    const int a_m = t >> 2,       a_k = (t & 3) << 2;
    const int b_k = t >> 4,       b_n = (t & 15) << 2;
    const int tm  = (t & 15) << 2, tn = (t >> 4) << 2;

    float acc[4][4] = {};
    const float* Aptr = A + (bm + a_m) * lda + a_k;
    const float* Bptr = B + b_k * ldb + bn + b_n;

    for (int k0 = 0; k0 < K; k0 += 16) {
        float4 av = *(const float4*)(Aptr + k0);
        float4 bv = *(const float4*)(Bptr + k0 * ldb);
        __syncthreads();
        As[a_k + 0][a_m] = av.x;
        As[a_k + 1][a_m] = av.y;
        As[a_k + 2][a_m] = av.z;
        As[a_k + 3][a_m] = av.w;
        *(float4*)(&Bs[b_k][b_n]) = bv;
        __syncthreads();
#pragma unroll
        for (int kk = 0; kk < 16; ++kk) {
            float4 a4 = *(const float4*)(&As[kk][tm]);
            float4 b4 = *(const float4*)(&Bs[kk][tn]);
            acc[0][0] += a4.x * b4.x; acc[0][1] += a4.x * b4.y; acc[0][2] += a4.x * b4.z; acc[0][3] += a4.x * b4.w;
            acc[1][0] += a4.y * b4.x; acc[1][1] += a4.y * b4.y; acc[1][2] += a4.y * b4.z; acc[1][3] += a4.y * b4.w;
            acc[2][0] += a4.z * b4.x; acc[2][1] += a4.z * b4.y; acc[2][2] += a4.z * b4.z; acc[2][3] += a4.z * b4.w;
            acc[3][0] += a4.w * b4.x; acc[3][1] += a4.w * b4.y; acc[3][2] += a4.w * b4.z; acc[3][3] += a4.w * b4.w;
        }
    }

    float4 bb = make_float4(0.f, 0.f, 0.f, 0.f);
    if (bias) bb = *(const float4*)(bias + bn + tn);
#pragma unroll
    for (int i = 0; i < 4; ++i) {
        float4 o;
        o.x = acc[i][0] + bb.x; o.y = acc[i][1] + bb.y;
        o.z = acc[i][2] + bb.z; o.w = acc[i][3] + bb.w;
        if (dorelu) { o.x = relu(o.x); o.y = relu(o.y); o.z = relu(o.z); o.w = relu(o.w); }
        *(float4*)(C + (bm + tm + i) * ldc + bn + tn) = o;
    }
}

// Per (b,i): Ehat[row] = [ sum_j adj*relu(hi_p + hj) (256) | deg | zeros(15) ]
__global__ __launch_bounds__(256) void msg_kernel(
    const float* __restrict__ hcat,   // (1024 x 1280): [hi_p | hj | gh]
    const int*   __restrict__ adj,    // (1024 x 256)
    float* __restrict__ Ehat)         // (1024 x 272)
{
    const int row = blockIdx.x;
    const int t = threadIdx.x;
    __shared__ float adjf[256];
    adjf[t] = (float)adj[row * 256 + t];
    const float hi = hcat[row * 1280 + t];
    const float* hjb = hcat + (row >> 8) * 256 * 1280 + 256;
    __syncthreads();
    float acc = 0.f, cnt = 0.f;
#pragma unroll 4
    for (int j = 0; j < 256; ++j) {
        float a = adjf[j];
        float v = hi + hjb[j * 1280 + t];
        acc += a * relu(v);
        cnt += a;
    }
    Ehat[row * 272 + t] = acc;
    if (t < 16) Ehat[row * 272 + 256 + t] = 0.f;
    if (t == 0) Ehat[row * 272 + 256] = cnt;
}

__global__ __launch_bounds__(256) void gru_kernel(
    const float* __restrict__ gi,     // (1024 x 768)
    const float* __restrict__ hcat,   // gh at col 512
    float* __restrict__ h)
{
    const int row = blockIdx.x;
    const int t = threadIdx.x;
    const float* gir = gi + row * 768;
    const float* ghr = hcat + row * 1280 + 512;
    float ir = gir[t], iz = gir[256 + t], in = gir[512 + t];
    float hr = ghr[t], hz = ghr[256 + t], hn = ghr[512 + t];
    float r = 1.f / (1.f + __expf(-(ir + hr)));
    float z = 1.f / (1.f + __expf(-(iz + hz)));
    float n = tanhf(in + r * hn);
    float ho = h[row * 256 + t];
    h[row * 256 + t] = (1.f - z) * n + z * ho;
}

__global__ __launch_bounds__(256) void readout_kernel(
    const float* __restrict__ h,
    const float* __restrict__ roW1, const float* __restrict__ rob1,
    const float* __restrict__ roW2, const float* __restrict__ rob2,
    void* __restrict__ out, const int* __restrict__ flagp)
{
    const int b = blockIdx.x;
    const int t = threadIdx.x;
    __shared__ float gl[256], t1[256];
    const float* hb = h + b * 256 * 256;
    float s = 0.f;
    for (int n = 0; n < 256; ++n) s += hb[n * 256 + t];
    gl[t] = s;
    __syncthreads();
    float acc = rob1[t];
    for (int k = 0; k < 256; ++k) acc += gl[k] * roW1[k * 256 + t];
    t1[t] = relu(acc);
    __syncthreads();
    if (t < 16) {
        float q = rob2[t];
        for (int k = 0; k < 256; ++k) q += t1[k] * roW2[k * 16 + t];
        if (*flagp) ((float*)out)[b * 16 + t] = q;
        else ((__hip_bfloat16*)out)[b * 16 + t] = __float2bfloat16(q);
    }
}

static inline void gemm(hipStream_t s, const float* A, int lda, const float* B, int ldb,
                        const float* bias, float* C, int ldc, int M, int N, int K, int relu_) {
    dim3 g(N / 64, M / 64);
    gemm_k<<<g, 256, 0, s>>>(A, lda, B, ldb, bias, C, ldc, K, relu_);
}

extern "C" void kernel_launch(void* const* d_in, const int* in_sizes, int n_in,
                              void* d_out, int out_size, void* d_ws, size_t ws_size,
                              hipStream_t stream) {
    float* w = (float*)d_ws;
    int* flagp = (int*)(w + OFF_FLAG);

    // --- input-order robustness: dict order vs alphabetical-key order ---
    static const int dictSz[18]  = {65536,262144,16384,256,65536,256,131072,256,65536,256,
                                    196608,196608,768,768,65536,256,4096,16};
    // alpha key order: adjacency,gru_Whh,gru_Wih,gru_bhh,gru_bih,msg_W1,msg_W2,msg_b1,msg_b2,
    //                  node_features,pre_W1,pre_W2,pre_b1,pre_b2,ro_W1,ro_W2,ro_b1,ro_b2
    static const int alphaSz[18] = {262144,196608,196608,768,768,131072,65536,256,256,
                                    65536,16384,65536,256,256,65536,4096,256,16};
    static const int alphaPos[18] = {9,0,10,12,11,13,5,7,6,8,2,1,4,3,14,16,15,17};
    bool dictOK = true, alphaOK = true;
    for (int i = 0; i < 18 && i < n_in; ++i) {
        if (in_sizes[i] != dictSz[i])  dictOK = false;
        if (in_sizes[i] != alphaSz[i]) alphaOK = false;
    }
    const void* P[18];
    for (int l = 0; l < 18; ++l) P[l] = d_in[(!dictOK && alphaOK) ? alphaPos[l] : l];
    const int* adj = (const int*)P[1];

    detect_kernel<<<1, 256, 0, stream>>>((const unsigned short*)P[0], flagp);

    convert_kernel<<<(CONV_TOTAL + 255) / 256, 256, 0, stream>>>(
        P[0], P[2], P[3], P[4], P[5], P[6], P[7], P[8], P[9],
        P[10], P[11], P[12], P[13], P[14], P[15], P[16], P[17], w, flagp);

    // pre-net: X = relu(NF @ preW1 + b1); h = X @ preW2 + b2
    gemm(stream, w + OFF_NF, FDIM, w + OFF_PREW1, HDIM, w + OFF_PREB1,
         w + OFF_X, HDIM, BN_ROWS, HDIM, FDIM, 1);
    gemm(stream, w + OFF_X, HDIM, w + OFF_PREW2, HDIM, w + OFF_PREB2,
         w + OFF_H, HDIM, BN_ROWS, HDIM, HDIM, 0);

    for (int it = 0; it < 3; ++it) {
        gemm(stream, w + OFF_H, HDIM, w + OFF_WCAT, 1280, w + OFF_BCAT,
             w + OFF_HCAT, 1280, BN_ROWS, 1280, HDIM, 0);
        msg_kernel<<<BN_ROWS, 256, 0, stream>>>(w + OFF_HCAT, adj, w + OFF_EHAT);
        gemm(stream, w + OFF_EHAT, 272, w + OFF_W2HAT, HDIM, nullptr,
             w + OFF_AGG, HDIM, BN_ROWS, HDIM, 272, 0);
        gemm(stream, w + OFF_AGG, HDIM, w + OFF_WIH, 768, w + OFF_BIH,
             w + OFF_GI, 768, BN_ROWS, 768, HDIM, 0);
        gru_kernel<<<BN_ROWS, 256, 0, stream>>>(w + OFF_GI, w + OFF_HCAT, w + OFF_H);
    }

    readout_kernel<<<4, 256, 0, stream>>>(w + OFF_H, w + OFF_ROW1, w + OFF_ROB1,
                                          w + OFF_ROW2, w + OFF_ROB2, d_out, flagp);
}

// Round 4
// 370.100 us; speedup vs baseline: 1.1352x; 1.1352x over previous
//
#include <hip/hip_runtime.h>
#include <hip/hip_bf16.h>

// B=4, N=256, F=64, H=256, A=16, T=3.  BN=1024 rows.
// bf16 inputs (runtime-verified); adjacency int32.
// GEMMs: bf16 MFMA 16x16x32. Weights are EXACT in bf16 (inputs are bf16).
// Precision: activations h/Ehat/agg stored as split hi/lo bf16 pairs along K,
// weights duplicated along K -> A_hi@B + A_lo@B in one MFMA GEMM (~fp32 acc).

typedef unsigned short ushort_t;
typedef short bf8_t __attribute__((ext_vector_type(8)));
typedef float f4_t  __attribute__((ext_vector_type(4)));

#define BN_ROWS 1024

// ---- bf16 regions (USHORT offsets) ----
#define UB_NFB    0         // 65536   NF [1024][64] (exact)
#define UB_PW1T   65536     // 16384   preW1^T [256][64]
#define UB_PW2T   81920     // 65536   preW2^T [256][256]
#define UB_WCATT  147456    // 655360  Wcat^T dup [1280][512]
#define UB_W2HT   802816    // 147456  W2hat^T dup [256][576]
#define UB_WIHT   950272    // 393216  Wih^T dup [768][512]
#define UB_XB     1343488   // 262144  X [1024][256] single bf16
#define UB_H2     1605632   // 524288  h  [1024][512] hi|lo
#define UB_EHAT2  2129920   // 589824  Ehat [1024][576] hi(288)|lo(288)
#define UB_AGG2   2719744   // 524288  agg [1024][512] hi|lo
#define UB_END    3244032   // -> 1622016 floats

// ---- fp32 regions (FLOAT offsets), contiguous from F_PREB1 ----
#define F_PREB1   1622016   // 256
#define F_PREB2   1622272   // 256
#define F_BCAT    1622528   // 1280  [msg_b1 | 0 | gru_bhh]
#define F_BIH     1623808   // 768
#define F_ROW1    1624576   // 65536
#define F_ROB1    1690112   // 256
#define F_ROW2    1690368   // 4096
#define F_ROB2    1694464   // 16
#define F_H       1694480   // 262144
#define F_HCAT    1956624   // 1310720 [hi_p | hj | gh]
#define F_GI      3267344   // 786432
#define F_FLAG    4053776   // 1 int        (total ~16.2 MiB)

// ---- convert index space ----
#define CVa 65536     // end NFB
#define CVb 81920     // end PW1T
#define CVc 147456    // end PW2T
#define CVd 802816    // end WCATT
#define CVe 950272    // end W2HT
#define CVf 1343488   // end WIHT
#define CV_TOTAL 1415952   // + 72464 fp32 tail

__device__ __forceinline__ float bf2f(ushort_t u) {
    return __uint_as_float(((unsigned int)u) << 16);
}
__device__ __forceinline__ ushort_t f2b(float v) {
    __hip_bfloat16 b = __float2bfloat16(v);
    return *reinterpret_cast<ushort_t*>(&b);
}
__device__ __forceinline__ float relu(float v) { return v < 0.f ? 0.f : v; }  // NaN-propagating
__device__ __forceinline__ float ld(const void* p, int i, int isf32) {
    return isf32 ? ((const float*)p)[i] : bf2f(((const ushort_t*)p)[i]);
}

__global__ __launch_bounds__(256) void detect_kernel(const ushort_t* __restrict__ nf,
                                                     int* __restrict__ flag) {
    __shared__ int cnt;
    if (threadIdx.x == 0) cnt = 0;
    __syncthreads();
    int bad = 0;
    for (int i = 0; i < 8; ++i) {
        ushort_t u = nf[(threadIdx.x * 8 + i) * 2];
        int ex = (u >> 7) & 0xFF;
        if ((u & 0x7fff) != 0 && (ex < 100 || ex > 140)) bad++;
    }
    atomicAdd(&cnt, bad);
    __syncthreads();
    if (threadIdx.x == 0) *flag = (cnt > 512) ? 1 : 0;
}

__global__ __launch_bounds__(256) void convert_kernel(
    const void* nf, const void* preW1, const void* preb1, const void* preW2, const void* preb2,
    const void* msgW1, const void* msgb1, const void* msgW2, const void* msgb2,
    const void* gruWih, const void* gruWhh, const void* grubih, const void* grubhh,
    const void* roW1, const void* rob1, const void* roW2, const void* rob2,
    float* __restrict__ w, const int* __restrict__ flagp)
{
    int e = blockIdx.x * 256 + threadIdx.x;
    if (e >= CV_TOTAL) return;
    const int f32 = *flagp;
    ushort_t* wb = (ushort_t*)w;
    if (e < CVa) {                                    // NF
        wb[UB_NFB + e] = f2b(ld(nf, e, f32));
    } else if (e < CVb) {                             // preW1^T [256][64]
        int i = e - CVa; int n = i >> 6, k = i & 63;
        wb[UB_PW1T + i] = f2b(ld(preW1, k * 256 + n, f32));
    } else if (e < CVc) {                             // preW2^T [256][256]
        int i = e - CVb; int n = i >> 8, k = i & 255;
        wb[UB_PW2T + i] = f2b(ld(preW2, k * 256 + n, f32));
    } else if (e < CVd) {                             // Wcat^T dup [1280][512]
        int i = e - CVc; int n = i >> 9, k = (i & 511) & 255;
        float v;
        if (n < 256)      v = ld(msgW1, k * 256 + n, f32);
        else if (n < 512) v = ld(msgW1, (256 + k) * 256 + (n - 256), f32);
        else              v = ld(gruWhh, k * 768 + (n - 512), f32);
        wb[UB_WCATT + i] = f2b(v);
    } else if (e < CVe) {                             // W2hat^T dup [256][576]
        int i = e - CVd; int n = i / 576, k = i - n * 576, km = k % 288;
        float v;
        if (km < 256)       v = ld(msgW2, km * 256 + n, f32);
        else if (km == 256) v = ld(msgb2, n, f32);    // deg column -> + deg*b2
        else                v = 0.f;
        wb[UB_W2HT + i] = f2b(v);
    } else if (e < CVf) {                             // Wih^T dup [768][512]
        int i = e - CVe; int n = i >> 9, k = i & 255;
        wb[UB_WIHT + i] = f2b(ld(gruWih, k * 768 + n, f32));
    } else {                                          // fp32 tail (contiguous)
        int f = e - CVf;
        float v;
        if (f < 256)        v = ld(preb1, f, f32);
        else if (f < 512)   v = ld(preb2, f - 256, f32);
        else if (f < 1792) {
            int c = f - 512;
            if (c < 256)      v = ld(msgb1, c, f32);
            else if (c < 512) v = 0.f;
            else              v = ld(grubhh, c - 512, f32);
        }
        else if (f < 2560)  v = ld(grubih, f - 1792, f32);
        else if (f < 68096) v = ld(roW1, f - 2560, f32);
        else if (f < 68352) v = ld(rob1, f - 68096, f32);
        else if (f < 72448) v = ld(roW2, f - 68352, f32);
        else                v = ld(rob2, f - 72448, f32);
        w[F_PREB1 + f] = v;
    }
}

// bf16 MFMA GEMM: C[M,N] = A[M,K] @ Bt[N,K]^T (+bias) (+relu).
// C (fp32) optional; Cb (bf16) optional with row stride cbld; if cblo!=0 also
// writes lo residual at col offset cblo (split hi/lo output).
// Block tile 128x128, 4 waves of 64x64. M,N %128==0; K %32==0.
__global__ __launch_bounds__(256) void mgemm_k(
    const ushort_t* __restrict__ A,
    const ushort_t* __restrict__ Bt,
    const float* __restrict__ bias,
    float* __restrict__ C,
    ushort_t* __restrict__ Cb, int cbld, int cblo,
    int K, int N, int dorelu)
{
    __shared__ ushort_t As[128 * 32];
    __shared__ ushort_t Bs[128 * 32];
    const int t = threadIdx.x;
    const int wave = t >> 6, lane = t & 63;
    const int ln = lane & 15, quad = lane >> 4;
    const int bm = blockIdx.y * 128, bn = blockIdx.x * 128;
    const int wm = (wave >> 1) * 64, wn = (wave & 1) * 64;
    const int srow = t >> 2, skc = (t & 3) << 3;

    f4_t acc[4][4] = {};

    for (int k0 = 0; k0 < K; k0 += 32) {
        __syncthreads();
#pragma unroll
        for (int r = 0; r < 2; ++r) {
            int row = srow + r * 64;
            *(bf8_t*)(&As[row * 32 + skc]) = *(const bf8_t*)(&A[(bm + row) * K + k0 + skc]);
            *(bf8_t*)(&Bs[row * 32 + skc]) = *(const bf8_t*)(&Bt[(bn + row) * K + k0 + skc]);
        }
        __syncthreads();
        bf8_t af[4], bfr[4];
#pragma unroll
        for (int i = 0; i < 4; ++i) {
            af[i]  = *(const bf8_t*)(&As[(wm + i * 16 + ln) * 32 + quad * 8]);
            bfr[i] = *(const bf8_t*)(&Bs[(wn + i * 16 + ln) * 32 + quad * 8]);
        }
#pragma unroll
        for (int mi = 0; mi < 4; ++mi)
#pragma unroll
            for (int ni = 0; ni < 4; ++ni)
                acc[mi][ni] = __builtin_amdgcn_mfma_f32_16x16x32_bf16(
                    af[mi], bfr[ni], acc[mi][ni], 0, 0, 0);
    }

#pragma unroll
    for (int mi = 0; mi < 4; ++mi) {
#pragma unroll
        for (int ni = 0; ni < 4; ++ni) {
            int col = bn + wn + ni * 16 + ln;
            float bb = bias ? bias[col] : 0.f;
#pragma unroll
            for (int r = 0; r < 4; ++r) {
                int row = bm + wm + mi * 16 + quad * 4 + r;
                float v = acc[mi][ni][r] + bb;
                if (dorelu) v = relu(v);
                if (C) C[row * N + col] = v;
                if (Cb) {
                    ushort_t hi = f2b(v);
                    Cb[row * cbld + col] = hi;
                    if (cblo) Cb[row * cbld + cblo + col] = f2b(v - bf2f(hi));
                }
            }
        }
    }
}

// Ehat2[row] (width 576, hi|lo): [ sum_{j:adj=1} relu(hi_p+hj) (256) | deg | 0 ]
__global__ __launch_bounds__(256) void msg_kernel(
    const float* __restrict__ hcat,   // [1024][1280]: [hi_p | hj | gh]
    const int*   __restrict__ adj,    // [1024][256]
    ushort_t* __restrict__ ehat)      // [1024][576]
{
    const int row = blockIdx.x;
    const int t = threadIdx.x;
    __shared__ int ej[256];
    __shared__ int ecnt;
    if (t == 0) ecnt = 0;
    __syncthreads();
    if (adj[row * 256 + t]) { int p = atomicAdd(&ecnt, 1); ej[p] = t; }
    const float hi = hcat[row * 1280 + t];
    const float* hjb = hcat + (row >> 8) * 256 * 1280 + 256;
    __syncthreads();
    const int ne = ecnt;
    float acc = 0.f;
#pragma unroll 4
    for (int p = 0; p < ne; ++p) {
        int j = ej[p];
        acc += relu(hi + hjb[j * 1280 + t]);
    }
    ushort_t h16 = f2b(acc);
    ehat[row * 576 + t] = h16;
    ehat[row * 576 + 288 + t] = f2b(acc - bf2f(h16));
    if (t < 32) {
        ehat[row * 576 + 256 + t] = f2b(t == 0 ? (float)ne : 0.f);  // deg exact (<=256)
        ehat[row * 576 + 544 + t] = 0;
    }
}

__global__ __launch_bounds__(256) void gru_kernel(
    const float* __restrict__ gi,     // [1024][768]
    const float* __restrict__ hcat,   // gh at col 512
    float* __restrict__ h,            // fp32 h (in/out)
    ushort_t* __restrict__ h2)        // bf16 h hi|lo [1024][512]
{
    const int row = blockIdx.x;
    const int t = threadIdx.x;
    const float* gir = gi + row * 768;
    const float* ghr = hcat + row * 1280 + 512;
    float ir = gir[t], iz = gir[256 + t], in = gir[512 + t];
    float hr = ghr[t], hz = ghr[256 + t], hn = ghr[512 + t];
    float r = 1.f / (1.f + __expf(-(ir + hr)));
    float z = 1.f / (1.f + __expf(-(iz + hz)));
    float n = tanhf(in + r * hn);
    float ho = h[row * 256 + t];
    float hv = (1.f - z) * n + z * ho;
    h[row * 256 + t] = hv;
    ushort_t hb = f2b(hv);
    h2[row * 512 + t] = hb;
    h2[row * 512 + 256 + t] = f2b(hv - bf2f(hb));
}

__global__ __launch_bounds__(256) void readout_kernel(
    const float* __restrict__ h,
    const float* __restrict__ roW1, const float* __restrict__ rob1,
    const float* __restrict__ roW2, const float* __restrict__ rob2,
    void* __restrict__ out, const int* __restrict__ flagp)
{
    const int b = blockIdx.x;
    const int t = threadIdx.x;
    __shared__ float gl[256], t1[256];
    const float* hb = h + b * 256 * 256;
    float s = 0.f;
    for (int n = 0; n < 256; ++n) s += hb[n * 256 + t];
    gl[t] = s;
    __syncthreads();
    float acc = rob1[t];
    for (int k = 0; k < 256; ++k) acc += gl[k] * roW1[k * 256 + t];
    t1[t] = relu(acc);
    __syncthreads();
    if (t < 16) {
        float q = rob2[t];
        for (int k = 0; k < 256; ++k) q += t1[k] * roW2[k * 16 + t];
        if (*flagp) ((float*)out)[b * 16 + t] = q;
        else ((__hip_bfloat16*)out)[b * 16 + t] = __float2bfloat16(q);
    }
}

extern "C" void kernel_launch(void* const* d_in, const int* in_sizes, int n_in,
                              void* d_out, int out_size, void* d_ws, size_t ws_size,
                              hipStream_t stream) {
    float* w = (float*)d_ws;
    ushort_t* wb = (ushort_t*)d_ws;
    int* flagp = (int*)(w + F_FLAG);

    static const int dictSz[18]  = {65536,262144,16384,256,65536,256,131072,256,65536,256,
                                    196608,196608,768,768,65536,256,4096,16};
    static const int alphaSz[18] = {262144,196608,196608,768,768,131072,65536,256,256,
                                    65536,16384,65536,256,256,65536,4096,256,16};
    static const int alphaPos[18] = {9,0,10,12,11,13,5,7,6,8,2,1,4,3,14,16,15,17};
    bool dictOK = true, alphaOK = true;
    for (int i = 0; i < 18 && i < n_in; ++i) {
        if (in_sizes[i] != dictSz[i])  dictOK = false;
        if (in_sizes[i] != alphaSz[i]) alphaOK = false;
    }
    const void* P[18];
    for (int l = 0; l < 18; ++l) P[l] = d_in[(!dictOK && alphaOK) ? alphaPos[l] : l];
    const int* adj = (const int*)P[1];

    detect_kernel<<<1, 256, 0, stream>>>((const ushort_t*)P[0], flagp);
    convert_kernel<<<(CV_TOTAL + 255) / 256, 256, 0, stream>>>(
        P[0], P[2], P[3], P[4], P[5], P[6], P[7], P[8], P[9],
        P[10], P[11], P[12], P[13], P[14], P[15], P[16], P[17], w, flagp);

    // pre-net: X = relu(NF@preW1+b1) -> bf16 single; h = X@preW2+b2 -> fp32 + hi/lo
    mgemm_k<<<dim3(2, 8), 256, 0, stream>>>(
        wb + UB_NFB, wb + UB_PW1T, w + F_PREB1, (float*)nullptr,
        wb + UB_XB, 256, 0, 64, 256, 1);
    mgemm_k<<<dim3(2, 8), 256, 0, stream>>>(
        wb + UB_XB, wb + UB_PW2T, w + F_PREB2, w + F_H,
        wb + UB_H2, 512, 256, 256, 256, 0);

    for (int it = 0; it < 3; ++it) {
        // hcat = h @ [W1_i|W1_j|Whh] + [b1|0|bhh]   (A = h hi|lo, K=512)
        mgemm_k<<<dim3(10, 8), 256, 0, stream>>>(
            wb + UB_H2, wb + UB_WCATT, w + F_BCAT, w + F_HCAT,
            (ushort_t*)nullptr, 0, 0, 512, 1280, 0);
        msg_kernel<<<BN_ROWS, 256, 0, stream>>>(w + F_HCAT, adj, wb + UB_EHAT2);
        // agg = Ehat @ W2hat  (A = Ehat hi|lo, K=576; deg col folds msg_b2)
        mgemm_k<<<dim3(2, 8), 256, 0, stream>>>(
            wb + UB_EHAT2, wb + UB_W2HT, (const float*)nullptr, (float*)nullptr,
            wb + UB_AGG2, 512, 256, 576, 256, 0);
        // gi = agg @ Wih + bih  (A = agg hi|lo, K=512)
        mgemm_k<<<dim3(6, 8), 256, 0, stream>>>(
            wb + UB_AGG2, wb + UB_WIHT, w + F_BIH, w + F_GI,
            (ushort_t*)nullptr, 0, 0, 512, 768, 0);
        gru_kernel<<<BN_ROWS, 256, 0, stream>>>(w + F_GI, w + F_HCAT,
                                                w + F_H, wb + UB_H2);
    }

    readout_kernel<<<4, 256, 0, stream>>>(w + F_H, w + F_ROW1, w + F_ROB1,
                                          w + F_ROW2, w + F_ROB2, d_out, flagp);
}